// Round 3
// baseline (340.502 us; speedup 1.0000x reference)
//
#include <hip/hip_runtime.h>
#include <hip/hip_bf16.h>

// IWHT3Layer: 3 branches of (per-coeff matmul [16,12544,64]x[16,64,64]) +
// inverse 2D 4x4 WHT over the 16 coefficients + bias.
// Inputs: float32. Output: float32 (reference output dtype).
//
// Layout facts:
//   transIm: [16t][16b][28i][28j][64c] f32, site s = b*784+i*28+j (12544 sites)
//   weight : [16t][64c][64k] f32
//   out    : [16b][112][112][64k] f32, out[b][4i+p][4j+q][k]
//
// Plan: workgroup = 4 waves = one (branch, 16-site tile). Wave w -> channels
// 16w..16w+15. 16x16x32 bf16 MFMA: M=16 sites, N=16 channels, K=c (2 steps).
// x loaded as f32, converted to bf16 in-register. Weights pre-transposed +
// converted to bf16 in d_ws by a prep kernel. WHT done element-wise on the
// 16 float4 accumulators (C/D layout: n=lane&15, m=quad*4+reg).

typedef __attribute__((ext_vector_type(8))) short bf16x8;   // 8 bf16 (4 VGPRs)
typedef __attribute__((ext_vector_type(4))) float floatx4;  // MFMA C/D
typedef __attribute__((ext_vector_type(4))) float f32x4;

#define NSITES 12544
#define NTILES 784
#define OUT_PER_BRANCH 12845056  // 16*112*112*64
#define WT_ELEMS (3*16*64*64)

__device__ __forceinline__ short f32_to_bf16_bits(float f) {
    __hip_bfloat16 h = __float2bfloat16(f);  // RNE
    return *reinterpret_cast<short*>(&h);
}

__global__ void transpose_weights(const float* __restrict__ w0,
                                  const float* __restrict__ w1,
                                  const float* __restrict__ w2,
                                  __hip_bfloat16* __restrict__ wT) {
    int idx = blockIdx.x * blockDim.x + threadIdx.x;  // [0, 3*16*64*64)
    if (idx >= WT_ELEMS) return;
    int c  = idx & 63;
    int k  = (idx >> 6) & 63;
    int t  = (idx >> 12) & 15;
    int br = idx >> 16;
    const float* w = (br == 0) ? w0 : ((br == 1) ? w1 : w2);
    // wT[br][t][k][c] = bf16(w[br][t][c][k])
    wT[idx] = __float2bfloat16(w[(t * 64 + c) * 64 + k]);
}

template <bool USE_WT>
__global__ __launch_bounds__(256) void iwht_kernel(
    const float* __restrict__ x0, const float* __restrict__ x1,
    const float* __restrict__ x2,
    const float* __restrict__ w0, const float* __restrict__ w1,
    const float* __restrict__ w2,
    const __hip_bfloat16* __restrict__ wT,
    const float* __restrict__ b0, const float* __restrict__ b1,
    const float* __restrict__ b2,
    float* __restrict__ out) {
    int bx   = blockIdx.x;
    int br   = bx / NTILES;
    int tile = bx - br * NTILES;
    int lane = threadIdx.x & 63;
    int wave = threadIdx.x >> 6;
    int l15  = lane & 15;
    int quad = lane >> 4;
    int n    = wave * 16 + l15;  // output channel 0..63

    const float* x    = (br == 0) ? x0 : ((br == 1) ? x1 : x2);
    const float* w    = (br == 0) ? w0 : ((br == 1) ? w1 : w2);
    const float* bias = (br == 0) ? b0 : ((br == 1) ? b1 : b2);

    int srow = tile * 16 + l15;  // A-operand site row (m = lane&15)

    floatx4 acc[16];
#pragma unroll
    for (int t = 0; t < 16; t++) acc[t] = (floatx4){0.f, 0.f, 0.f, 0.f};

    // A: x[t][srow][c] f32, lane covers c = quad*8..+7 (a0) and +32 (a1)
    const float* xbase = x + (size_t)srow * 64 + quad * 8;

#pragma unroll
    for (int t = 0; t < 16; t++) {
        const f32x4* xv = reinterpret_cast<const f32x4*>(xbase + (size_t)t * NSITES * 64);
        f32x4 f0 = xv[0], f1 = xv[1];   // c = quad*8 .. +7
        f32x4 f2 = xv[8], f3 = xv[9];   // c = quad*8+32 .. +39
        bf16x8 a0, a1;
#pragma unroll
        for (int j = 0; j < 4; j++) {
            a0[j]     = f32_to_bf16_bits(f0[j]);
            a0[j + 4] = f32_to_bf16_bits(f1[j]);
            a1[j]     = f32_to_bf16_bits(f2[j]);
            a1[j + 4] = f32_to_bf16_bits(f3[j]);
        }
        bf16x8 bb0, bb1;
        if (USE_WT) {
            // B: wT[br][t][n][c] bf16, lane covers same c mapping as A
            const bf16x8* wv = reinterpret_cast<const bf16x8*>(
                wT + (((size_t)(br * 16 + t) * 64 + n) * 64) + quad * 8);
            bb0 = wv[0];
            bb1 = wv[4];  // +32 c elements
        } else {
            // fallback: strided f32 loads from original w[t][c][k], convert
#pragma unroll
            for (int j = 0; j < 8; j++) {
                int c0 = quad * 8 + j;
                bb0[j] = f32_to_bf16_bits(w[(t * 64 + c0) * 64 + n]);
                bb1[j] = f32_to_bf16_bits(w[(t * 64 + c0 + 32) * 64 + n]);
            }
        }
        acc[t] = __builtin_amdgcn_mfma_f32_16x16x32_bf16(a0, bb0, acc[t], 0, 0, 0);
        acc[t] = __builtin_amdgcn_mfma_f32_16x16x32_bf16(a1, bb1, acc[t], 0, 0, 0);
    }

    float biasf = bias[n];

    // Per accumulator reg r: site = tile*16 + quad*4 + r (m = quad*4+reg).
    size_t obase[4];
#pragma unroll
    for (int r = 0; r < 4; r++) {
        int site = tile * 16 + quad * 4 + r;
        int b    = site / 784;
        int rem  = site - b * 784;
        int i    = rem / 28;
        int j    = rem - i * 28;
        obase[r] = (size_t)br * OUT_PER_BRANCH +
                   (((size_t)(b * 112 + 4 * i)) * 112 + 4 * j) * 64 + n;
    }

    // Inverse WHT over v (t = 4u+v): acc[4u+q] = sum_v H[q][v] y[4u+v]
#pragma unroll
    for (int u = 0; u < 4; u++) {
        floatx4 y0 = acc[4 * u + 0], y1 = acc[4 * u + 1];
        floatx4 y2 = acc[4 * u + 2], y3 = acc[4 * u + 3];
        floatx4 A = y0 + y2, Bv = y1 + y3, Cv = y0 - y2, Dv = y1 - y3;
        acc[4 * u + 0] = A + Bv;
        acc[4 * u + 1] = A - Bv;
        acc[4 * u + 2] = Cv + Dv;
        acc[4 * u + 3] = Cv - Dv;
    }

    // Inverse WHT over u, then scale + bias + store (f32).
#pragma unroll
    for (int q = 0; q < 4; q++) {
        floatx4 z0 = acc[0 + q], z1 = acc[4 + q], z2 = acc[8 + q], z3 = acc[12 + q];
        floatx4 A = z0 + z2, Bv = z1 + z3, Cv = z0 - z2, Dv = z1 - z3;
        floatx4 o[4];
        o[0] = A + Bv;
        o[1] = A - Bv;
        o[2] = Cv + Dv;
        o[3] = Cv - Dv;
#pragma unroll
        for (int p = 0; p < 4; p++) {
#pragma unroll
            for (int r = 0; r < 4; r++) {
                float v = o[p][r] * 0.0625f + biasf;
                out[obase[r] + (size_t)(p * 112 + q) * 64] = v;
            }
        }
    }
}

extern "C" void kernel_launch(void* const* d_in, const int* in_sizes, int n_in,
                              void* d_out, int out_size, void* d_ws, size_t ws_size,
                              hipStream_t stream) {
    const float* x0 = (const float*)d_in[0];
    const float* x1 = (const float*)d_in[1];
    const float* x2 = (const float*)d_in[2];
    const float* w0 = (const float*)d_in[3];
    const float* w1 = (const float*)d_in[4];
    const float* w2 = (const float*)d_in[5];
    const float* b0 = (const float*)d_in[6];
    const float* b1 = (const float*)d_in[7];
    const float* b2 = (const float*)d_in[8];
    float* out = (float*)d_out;
    __hip_bfloat16* wT = (__hip_bfloat16*)d_ws;

    bool use_wt = ws_size >= (size_t)WT_ELEMS * sizeof(__hip_bfloat16);
    if (use_wt) {
        transpose_weights<<<(WT_ELEMS + 255) / 256, 256, 0, stream>>>(w0, w1, w2, wT);
        iwht_kernel<true><<<3 * NTILES, 256, 0, stream>>>(x0, x1, x2, w0, w1, w2, wT,
                                                          b0, b1, b2, out);
    } else {
        iwht_kernel<false><<<3 * NTILES, 256, 0, stream>>>(x0, x1, x2, w0, w1, w2, wT,
                                                           b0, b1, b2, out);
    }
}

// Round 4
// 301.137 us; speedup vs baseline: 1.1307x; 1.1307x over previous
//
#include <hip/hip_runtime.h>
#include <hip/hip_bf16.h>

// IWHT3Layer: 3 branches of (per-coeff matmul [16,12544,64]x[16,64,64]) +
// inverse 2D 4x4 WHT over the 16 coefficients + bias.
// Inputs: float32. Output: float32.
//
// R4 change vs R3 (147us, latency-bound, 1.6TB/s): x-tile staged into LDS via
// global_load_lds DMA (zero VGPR cost -> deep MLP), 4-t chunks double-buffered,
// padded 272B row stride so A ds_read_b128 is 2-way bank-aliased (free).
// B (weights, 384KB, L2-hot) stays as direct global bf16x8 loads from the
// pre-transposed wT. Matmul/WHT/epilogue identical to the verified R3 kernel.

typedef __attribute__((ext_vector_type(8))) short bf16x8;   // 8 bf16 (4 VGPRs)
typedef __attribute__((ext_vector_type(4))) float floatx4;  // MFMA C/D

#define NSITES 12544
#define NTILES 784
#define OUT_PER_BRANCH 12845056  // 16*112*112*64
#define WT_ELEMS (3*16*64*64)
#define ROW_F 68                 // LDS row stride in floats: 64 data + 4 pad
#define CHUNK_F (64 * ROW_F)     // 4 t * 16 rows = 64 rows per chunk (17408 B)

__device__ __forceinline__ short f32_to_bf16_bits(float f) {
    __hip_bfloat16 h = __float2bfloat16(f);  // RNE
    return *reinterpret_cast<short*>(&h);
}

__global__ void transpose_weights(const float* __restrict__ w0,
                                  const float* __restrict__ w1,
                                  const float* __restrict__ w2,
                                  __hip_bfloat16* __restrict__ wT) {
    int idx = blockIdx.x * blockDim.x + threadIdx.x;  // [0, 3*16*64*64)
    if (idx >= WT_ELEMS) return;
    int c  = idx & 63;
    int k  = (idx >> 6) & 63;
    int t  = (idx >> 12) & 15;
    int br = idx >> 16;
    const float* w = (br == 0) ? w0 : ((br == 1) ? w1 : w2);
    // wT[br][t][k][c] = bf16(w[br][t][c][k])
    wT[idx] = __float2bfloat16(w[(t * 64 + c) * 64 + k]);
}

template <bool USE_WT>
__global__ __launch_bounds__(256) void iwht_kernel(
    const float* __restrict__ x0, const float* __restrict__ x1,
    const float* __restrict__ x2,
    const float* __restrict__ w0, const float* __restrict__ w1,
    const float* __restrict__ w2,
    const __hip_bfloat16* __restrict__ wT,
    const float* __restrict__ b0, const float* __restrict__ b1,
    const float* __restrict__ b2,
    float* __restrict__ out) {
    __shared__ float xs[2][CHUNK_F];  // 2 x 17408 B = 34816 B

    int bx   = blockIdx.x;
    int br   = bx / NTILES;
    int tile = bx - br * NTILES;
    int lane = threadIdx.x & 63;
    int wave = threadIdx.x >> 6;
    int l15  = lane & 15;
    int quad = lane >> 4;
    int n    = wave * 16 + l15;  // output channel 0..63

    const float* x    = (br == 0) ? x0 : ((br == 1) ? x1 : x2);
    const float* w    = (br == 0) ? w0 : ((br == 1) ? w1 : w2);
    const float* bias = (br == 0) ? b0 : ((br == 1) ? b1 : b2);

    // DMA source base: row (t, s) starts at x + (t*NSITES + tile*16 + s)*64;
    // lane contributes 4 bytes at +lane.
    const float* xg = x + (size_t)(tile * 16) * 64 + lane;

    floatx4 acc[16];
#pragma unroll
    for (int t = 0; t < 16; t++) acc[t] = (floatx4){0.f, 0.f, 0.f, 0.f};

    // --- stage chunk g (t = 4g..4g+3) into xs[buf]: wave handles 16 rows ---
#define STAGE(g, buf)                                                          \
    {                                                                          \
        _Pragma("unroll") for (int r = 0; r < 16; r++) {                       \
            int row = wave * 16 + r; /* row = tl*16 + s */                     \
            int tl  = row >> 4;                                                \
            int s   = row & 15;                                                \
            const float* gp = xg + ((size_t)((g) * 4 + tl) * NSITES + s) * 64; \
            __builtin_amdgcn_global_load_lds(                                  \
                (const __attribute__((address_space(1))) void*)gp,             \
                (__attribute__((address_space(3))) void*)&xs[buf][row * ROW_F],\
                4, 0, 0);                                                      \
        }                                                                      \
    }

    STAGE(0, 0);
    __syncthreads();

#pragma unroll
    for (int g = 0; g < 4; g++) {
        int buf = g & 1;
        if (g < 3) STAGE(g + 1, buf ^ 1);
#pragma unroll
        for (int tl = 0; tl < 4; tl++) {
            int t = g * 4 + tl;
            // A: xs row (tl*16 + l15), c = quad*8..+7 and +32 (f32, 16B aligned)
            const float* rowp = &xs[buf][(tl * 16 + l15) * ROW_F + quad * 8];
            floatx4 f0 = ((const floatx4*)rowp)[0];
            floatx4 f1 = ((const floatx4*)rowp)[1];
            floatx4 f2 = ((const floatx4*)(rowp + 32))[0];
            floatx4 f3 = ((const floatx4*)(rowp + 32))[1];
            bf16x8 a0, a1;
#pragma unroll
            for (int j = 0; j < 4; j++) {
                a0[j]     = f32_to_bf16_bits(f0[j]);
                a0[j + 4] = f32_to_bf16_bits(f1[j]);
                a1[j]     = f32_to_bf16_bits(f2[j]);
                a1[j + 4] = f32_to_bf16_bits(f3[j]);
            }
            bf16x8 bb0, bb1;
            if (USE_WT) {
                // B: wT[br][t][n][c] bf16, same c<->k lane mapping as A
                const bf16x8* wv = reinterpret_cast<const bf16x8*>(
                    wT + (((size_t)(br * 16 + t) * 64 + n) * 64) + quad * 8);
                bb0 = wv[0];
                bb1 = wv[4];  // +32 c elements
            } else {
                // fallback: strided f32 loads from original w[t][c][k]
#pragma unroll
                for (int j = 0; j < 8; j++) {
                    int c0 = quad * 8 + j;
                    bb0[j] = f32_to_bf16_bits(w[(t * 64 + c0) * 64 + n]);
                    bb1[j] = f32_to_bf16_bits(w[(t * 64 + c0 + 32) * 64 + n]);
                }
            }
            acc[t] = __builtin_amdgcn_mfma_f32_16x16x32_bf16(a0, bb0, acc[t], 0, 0, 0);
            acc[t] = __builtin_amdgcn_mfma_f32_16x16x32_bf16(a1, bb1, acc[t], 0, 0, 0);
        }
        if (g < 3) __syncthreads();
    }
#undef STAGE

    float biasf = bias[n];

    // Per accumulator reg r: site = tile*16 + quad*4 + r (m = quad*4+reg).
    size_t obase[4];
#pragma unroll
    for (int r = 0; r < 4; r++) {
        int site = tile * 16 + quad * 4 + r;
        int b    = site / 784;
        int rem  = site - b * 784;
        int i    = rem / 28;
        int j    = rem - i * 28;
        obase[r] = (size_t)br * OUT_PER_BRANCH +
                   (((size_t)(b * 112 + 4 * i)) * 112 + 4 * j) * 64 + n;
    }

    // Inverse WHT over v (t = 4u+v): acc[4u+q] = sum_v H[q][v] y[4u+v]
#pragma unroll
    for (int u = 0; u < 4; u++) {
        floatx4 y0 = acc[4 * u + 0], y1 = acc[4 * u + 1];
        floatx4 y2 = acc[4 * u + 2], y3 = acc[4 * u + 3];
        floatx4 A = y0 + y2, Bv = y1 + y3, Cv = y0 - y2, Dv = y1 - y3;
        acc[4 * u + 0] = A + Bv;
        acc[4 * u + 1] = A - Bv;
        acc[4 * u + 2] = Cv + Dv;
        acc[4 * u + 3] = Cv - Dv;
    }

    // Inverse WHT over u, then scale + bias + store (f32).
#pragma unroll
    for (int q = 0; q < 4; q++) {
        floatx4 z0 = acc[0 + q], z1 = acc[4 + q], z2 = acc[8 + q], z3 = acc[12 + q];
        floatx4 A = z0 + z2, Bv = z1 + z3, Cv = z0 - z2, Dv = z1 - z3;
        floatx4 o[4];
        o[0] = A + Bv;
        o[1] = A - Bv;
        o[2] = Cv + Dv;
        o[3] = Cv - Dv;
#pragma unroll
        for (int p = 0; p < 4; p++) {
#pragma unroll
            for (int r = 0; r < 4; r++) {
                float v = o[p][r] * 0.0625f + biasf;
                out[obase[r] + (size_t)(p * 112 + q) * 64] = v;
            }
        }
    }
}

extern "C" void kernel_launch(void* const* d_in, const int* in_sizes, int n_in,
                              void* d_out, int out_size, void* d_ws, size_t ws_size,
                              hipStream_t stream) {
    const float* x0 = (const float*)d_in[0];
    const float* x1 = (const float*)d_in[1];
    const float* x2 = (const float*)d_in[2];
    const float* w0 = (const float*)d_in[3];
    const float* w1 = (const float*)d_in[4];
    const float* w2 = (const float*)d_in[5];
    const float* b0 = (const float*)d_in[6];
    const float* b1 = (const float*)d_in[7];
    const float* b2 = (const float*)d_in[8];
    float* out = (float*)d_out;
    __hip_bfloat16* wT = (__hip_bfloat16*)d_ws;

    bool use_wt = ws_size >= (size_t)WT_ELEMS * sizeof(__hip_bfloat16);
    if (use_wt) {
        transpose_weights<<<(WT_ELEMS + 255) / 256, 256, 0, stream>>>(w0, w1, w2, wT);
        iwht_kernel<true><<<3 * NTILES, 256, 0, stream>>>(x0, x1, x2, w0, w1, w2, wT,
                                                          b0, b1, b2, out);
    } else {
        iwht_kernel<false><<<3 * NTILES, 256, 0, stream>>>(x0, x1, x2, w0, w1, w2, wT,
                                                           b0, b1, b2, out);
    }
}